// Round 2
// baseline (518.621 us; speedup 1.0000x reference)
//
#include <hip/hip_runtime.h>

typedef float        f32x4  __attribute__((ext_vector_type(4)));
typedef __bf16       bf16x8 __attribute__((ext_vector_type(8)));
typedef unsigned int u32x4  __attribute__((ext_vector_type(4)));

#define NN   8192
#define IND  256
#define OUTD 128
#define NB   144   // 9 n-tiles of 16: cols 0..127 = w*Wh, col 128 = w (denominator), 129..143 = 0
#define KSPLIT 4

__device__ __forceinline__ bf16x8 cvt2(f32x4 a, f32x4 b) {
  bf16x8 r;
  r[0]=(__bf16)a[0]; r[1]=(__bf16)a[1]; r[2]=(__bf16)a[2]; r[3]=(__bf16)a[3];
  r[4]=(__bf16)b[0]; r[5]=(__bf16)b[1]; r[6]=(__bf16)b[2]; r[7]=(__bf16)b[3];
  return r;
}

// K1: Wh = X @ W^T   [8192,128] fp32, e[j] = relu(Wh[j]) . a_w
__global__ __launch_bounds__(128) void k1_wh_e(const float* __restrict__ X,
                                               const float* __restrict__ W,
                                               const float* __restrict__ aw,
                                               float* __restrict__ Wh,
                                               float* __restrict__ ev) {
  const int lane = threadIdx.x & 63;
  const int wave = threadIdx.x >> 6;
  const int nlo  = lane & 15;
  const int quad = lane >> 4;
  const int rowBase = blockIdx.x * 32 + wave * 16;

  const float* xp = X + (size_t)(rowBase + nlo) * IND + quad * 8;
  f32x4 acc[8];
#pragma unroll
  for (int nt = 0; nt < 8; ++nt) acc[nt] = f32x4{0.f, 0.f, 0.f, 0.f};

#pragma unroll
  for (int kb = 0; kb < IND; kb += 32) {
    f32x4 a0 = *(const f32x4*)(xp + kb);
    f32x4 a1 = *(const f32x4*)(xp + kb + 4);
    bf16x8 af = cvt2(a0, a1);
#pragma unroll
    for (int nt = 0; nt < 8; ++nt) {
      const float* wp = W + (size_t)(nt * 16 + nlo) * IND + kb + quad * 8;
      f32x4 b0 = *(const f32x4*)wp;
      f32x4 b1 = *(const f32x4*)(wp + 4);
      acc[nt] = __builtin_amdgcn_mfma_f32_16x16x32_bf16(af, cvt2(b0, b1), acc[nt], 0, 0, 0);
    }
  }
  float p0 = 0.f, p1 = 0.f, p2 = 0.f, p3 = 0.f;
#pragma unroll
  for (int nt = 0; nt < 8; ++nt) {
    const int col = nt * 16 + nlo;
    const float awc = aw[col];
    const int r0 = rowBase + quad * 4;
    float v0 = acc[nt][0], v1 = acc[nt][1], v2 = acc[nt][2], v3 = acc[nt][3];
    Wh[(size_t)(r0 + 0) * OUTD + col] = v0;
    Wh[(size_t)(r0 + 1) * OUTD + col] = v1;
    Wh[(size_t)(r0 + 2) * OUTD + col] = v2;
    Wh[(size_t)(r0 + 3) * OUTD + col] = v3;
    p0 += fmaxf(v0, 0.f) * awc;
    p1 += fmaxf(v1, 0.f) * awc;
    p2 += fmaxf(v2, 0.f) * awc;
    p3 += fmaxf(v3, 0.f) * awc;
  }
#pragma unroll
  for (int off = 8; off; off >>= 1) {
    p0 += __shfl_xor(p0, off, 64);
    p1 += __shfl_xor(p1, off, 64);
    p2 += __shfl_xor(p2, off, 64);
    p3 += __shfl_xor(p3, off, 64);
  }
  if (nlo == 0) {
    const int r0 = rowBase + quad * 4;
    ev[r0 + 0] = p0; ev[r0 + 1] = p1; ev[r0 + 2] = p2; ev[r0 + 3] = p3;
  }
}

// K2: build B^T [NB][NN] bf16: row n<128: w_j*Wh[j][n]; row 128: w_j; rows 129..143: 0
__global__ __launch_bounds__(256) void k2_bt(const float* __restrict__ Wh,
                                             const float* __restrict__ ev,
                                             __bf16* __restrict__ Bt) {
  const int j = blockIdx.x * 256 + threadIdx.x;
  const float w = expf(ev[j]);
  const int n0 = blockIdx.y * 18;
#pragma unroll
  for (int i = 0; i < 18; ++i) {
    const int n = n0 + i;
    float v = 0.f;
    if (n < OUTD) v = w * Wh[(size_t)j * OUTD + n];
    else if (n == OUTD) v = w;
    Bt[(size_t)n * NN + j] = (__bf16)v;
  }
}

// K3a: partial C[kslice][8192 x 144] = Adj_slice(bf16) @ B_slice
// grid (512, KSPLIT) x 256 threads. WG = 16 rows; 4 waves split the 2048-k
// slice into 4x512. LDS cross-wave reduce, wave0 stores 16x144 fp32 partial.
__global__ __launch_bounds__(256, 4) void k3_partial(const float* __restrict__ Adj,
                                                     const __bf16* __restrict__ Bt,
                                                     float* __restrict__ part) {
  __shared__ float red[3][16][145];  // 27.8 KB
  const int lane = threadIdx.x & 63;
  const int wave = threadIdx.x >> 6;
  const int nlo  = lane & 15;
  const int quad = lane >> 4;
  const int rowBase = blockIdx.x * 16;
  const int k0 = blockIdx.y * 2048 + wave * 512;

  f32x4 acc[9];
#pragma unroll
  for (int nt = 0; nt < 9; ++nt) acc[nt] = f32x4{0.f, 0.f, 0.f, 0.f};

  const float*  ap = Adj + (size_t)(rowBase + nlo) * NN + quad * 8 + k0;
  const __bf16* bp = Bt + (size_t)nlo * NN + quad * 8 + k0;

  for (int kb = 0; kb < 512; kb += 32) {
    f32x4 x0 = __builtin_nontemporal_load((const f32x4*)(ap + kb));
    f32x4 x1 = __builtin_nontemporal_load((const f32x4*)(ap + kb + 4));
    u32x4 braw[9];
#pragma unroll
    for (int nt = 0; nt < 9; ++nt)
      braw[nt] = *(const u32x4*)(bp + (size_t)nt * 16 * NN + kb);
    bf16x8 af = cvt2(x0, x1);
#pragma unroll
    for (int nt = 0; nt < 9; ++nt)
      acc[nt] = __builtin_amdgcn_mfma_f32_16x16x32_bf16(af, __builtin_bit_cast(bf16x8, braw[nt]), acc[nt], 0, 0, 0);
  }

  if (wave) {
    float (*slot)[145] = red[wave - 1];
#pragma unroll
    for (int nt = 0; nt < 9; ++nt)
#pragma unroll
      for (int rg = 0; rg < 4; ++rg)
        slot[quad * 4 + rg][nt * 16 + nlo] = acc[nt][rg];
  }
  __syncthreads();
  if (wave == 0) {
    float* pbase = part + ((size_t)blockIdx.y * NN + rowBase) * NB;
#pragma unroll
    for (int nt = 0; nt < 9; ++nt)
#pragma unroll
      for (int rg = 0; rg < 4; ++rg) {
        const int r = quad * 4 + rg;
        const int c = nt * 16 + nlo;
        pbase[(size_t)r * NB + c] = acc[nt][rg] + red[0][r][c] + red[1][r][c] + red[2][r][c];
      }
  }
}

// K3b: out[row][col] = relu( sum_s part[s][row][col] / sum_s part[s][row][128] )
__global__ __launch_bounds__(256) void k3_reduce(const float* __restrict__ part,
                                                 float* __restrict__ out) {
  const int col = threadIdx.x & 127;
  const int row = blockIdx.x * 2 + (threadIdx.x >> 7);
  float num = 0.f, den = 0.f;
#pragma unroll
  for (int s = 0; s < KSPLIT; ++s) {
    const size_t base = ((size_t)s * NN + row) * NB;
    num += part[base + col];
    den += part[base + 128];
  }
  out[(size_t)row * OUTD + col] = fmaxf(num / den, 0.f);
}

extern "C" void kernel_launch(void* const* d_in, const int* in_sizes, int n_in,
                              void* d_out, int out_size, void* d_ws, size_t ws_size,
                              hipStream_t stream) {
  const float* X  = (const float*)d_in[0];
  const float* A  = (const float*)d_in[1];
  const float* W  = (const float*)d_in[2];
  const float* aw = (const float*)d_in[3];
  float* out = (float*)d_out;

  char* ws = (char*)d_ws;
  float*  Wh   = (float*)ws;                    // 8192*128*4  = 4 MiB
  float*  ev   = (float*)(ws + 4194304);        // 8192*4      = 32 KiB
  __bf16* Bt   = (__bf16*)(ws + 4227072);       // 144*8192*2  = 2.25 MiB
  float*  part = (float*)(ws + 8388608);        // 4*8192*144*4 = 18.9 MiB

  k1_wh_e<<<256, 128, 0, stream>>>(X, W, aw, Wh, ev);
  k2_bt<<<dim3(32, 8), 256, 0, stream>>>(Wh, ev, Bt);
  k3_partial<<<dim3(512, KSPLIT), 256, 0, stream>>>(A, Bt, part);
  k3_reduce<<<4096, 256, 0, stream>>>(part, out);
}

// Round 3
// 432.218 us; speedup vs baseline: 1.1999x; 1.1999x over previous
//
#include <hip/hip_runtime.h>

typedef float        f32x4  __attribute__((ext_vector_type(4)));
typedef __bf16       bf16x8 __attribute__((ext_vector_type(8)));
typedef unsigned int u32x4  __attribute__((ext_vector_type(4)));

#define NN   8192
#define IND  256
#define OUTD 128
#define NB   144    // cols 0..127 = w*Wh, col 128 = w (denominator), 129..143 = 0
#define KSPLIT 8
#define KRANGE 1024 // 8192 / KSPLIT
#define KCHUNK 128
#define BSTRIDE 136 // 128 + 8 bf16 pad: 272 B rows -> 2-way LDS aliasing only (free)

__device__ __forceinline__ bf16x8 cvt2(f32x4 a, f32x4 b) {
  bf16x8 r;
  r[0]=(__bf16)a[0]; r[1]=(__bf16)a[1]; r[2]=(__bf16)a[2]; r[3]=(__bf16)a[3];
  r[4]=(__bf16)b[0]; r[5]=(__bf16)b[1]; r[6]=(__bf16)b[2]; r[7]=(__bf16)b[3];
  return r;
}

// K1: Wh = X @ W^T  [8192,128] fp32; e[j] = relu(Wh[j]) . a_w
__global__ __launch_bounds__(128) void k1_wh_e(const float* __restrict__ X,
                                               const float* __restrict__ W,
                                               const float* __restrict__ aw,
                                               float* __restrict__ Wh,
                                               float* __restrict__ ev) {
  const int lane = threadIdx.x & 63;
  const int wave = threadIdx.x >> 6;
  const int nlo  = lane & 15;
  const int quad = lane >> 4;
  const int rowBase = blockIdx.x * 32 + wave * 16;

  const float* xp = X + (size_t)(rowBase + nlo) * IND + quad * 8;
  f32x4 acc[8];
#pragma unroll
  for (int nt = 0; nt < 8; ++nt) acc[nt] = f32x4{0.f, 0.f, 0.f, 0.f};

#pragma unroll
  for (int kb = 0; kb < IND; kb += 32) {
    f32x4 a0 = *(const f32x4*)(xp + kb);
    f32x4 a1 = *(const f32x4*)(xp + kb + 4);
    bf16x8 af = cvt2(a0, a1);
#pragma unroll
    for (int nt = 0; nt < 8; ++nt) {
      const float* wp = W + (size_t)(nt * 16 + nlo) * IND + kb + quad * 8;
      f32x4 b0 = *(const f32x4*)wp;
      f32x4 b1 = *(const f32x4*)(wp + 4);
      acc[nt] = __builtin_amdgcn_mfma_f32_16x16x32_bf16(af, cvt2(b0, b1), acc[nt], 0, 0, 0);
    }
  }
  float p0 = 0.f, p1 = 0.f, p2 = 0.f, p3 = 0.f;
#pragma unroll
  for (int nt = 0; nt < 8; ++nt) {
    const int col = nt * 16 + nlo;
    const float awc = aw[col];
    const int r0 = rowBase + quad * 4;
    float v0 = acc[nt][0], v1 = acc[nt][1], v2 = acc[nt][2], v3 = acc[nt][3];
    Wh[(size_t)(r0 + 0) * OUTD + col] = v0;
    Wh[(size_t)(r0 + 1) * OUTD + col] = v1;
    Wh[(size_t)(r0 + 2) * OUTD + col] = v2;
    Wh[(size_t)(r0 + 3) * OUTD + col] = v3;
    p0 += fmaxf(v0, 0.f) * awc;
    p1 += fmaxf(v1, 0.f) * awc;
    p2 += fmaxf(v2, 0.f) * awc;
    p3 += fmaxf(v3, 0.f) * awc;
  }
#pragma unroll
  for (int off = 8; off; off >>= 1) {
    p0 += __shfl_xor(p0, off, 64);
    p1 += __shfl_xor(p1, off, 64);
    p2 += __shfl_xor(p2, off, 64);
    p3 += __shfl_xor(p3, off, 64);
  }
  if (nlo == 0) {
    const int r0 = rowBase + quad * 4;
    ev[r0 + 0] = p0; ev[r0 + 1] = p1; ev[r0 + 2] = p2; ev[r0 + 3] = p3;
  }
}

// K2: B^T [NB][NN] bf16: row n<128: w_j*Wh[j][n]; row 128: w_j; rows 129..143: 0
__global__ __launch_bounds__(256) void k2_bt(const float* __restrict__ Wh,
                                             const float* __restrict__ ev,
                                             __bf16* __restrict__ Bt) {
  const int j = blockIdx.x * 256 + threadIdx.x;
  const float w = expf(ev[j]);
  const int n0 = blockIdx.y * 18;
#pragma unroll
  for (int i = 0; i < 18; ++i) {
    const int n = n0 + i;
    float v = 0.f;
    if (n < OUTD) v = w * Wh[(size_t)j * OUTD + n];
    else if (n == OUTD) v = w;
    Bt[(size_t)n * NN + j] = (__bf16)v;
  }
}

// K3a: part[slice][8192 x 144] += Adj(->bf16) @ B over slice's 1024-k range.
// Grid (128, KSPLIT) x 256. WG = 64 rows; waves split M (16 rows each), NOT K.
// B tile staged in LDS per 128-k chunk via coalesced loads; A register-direct.
__global__ __launch_bounds__(256, 4) void k3_partial(const float* __restrict__ Adj,
                                                     const __bf16* __restrict__ Bt,
                                                     float* __restrict__ part) {
  __shared__ unsigned short bt[NB * BSTRIDE];  // 38.25 KB
  const int tid  = threadIdx.x;
  const int lane = tid & 63;
  const int wave = tid >> 6;
  const int nlo  = lane & 15;
  const int quad = lane >> 4;
  const int rowW = blockIdx.x * 64 + wave * 16;   // wave's 16 rows
  const int k0   = blockIdx.y * KRANGE;

  const int brow = tid >> 4;        // 0..15, + rr*16 below
  const int bcol = (tid & 15) * 8;  // bf16 elems, 16B per thread

  f32x4 acc[9];
#pragma unroll
  for (int nt = 0; nt < 9; ++nt) acc[nt] = f32x4{0.f, 0.f, 0.f, 0.f};

  const float* ap = Adj + (size_t)(rowW + nlo) * NN + quad * 8 + k0;

  for (int c = 0; c < KRANGE / KCHUNK; ++c) {
    const int kc = k0 + c * KCHUNK;
    // B stage: issue global B loads FIRST so the ds_write wait leaves A in flight
    u32x4 breg[9];
#pragma unroll
    for (int rr = 0; rr < 9; ++rr)
      breg[rr] = *(const u32x4*)(Bt + (size_t)(rr * 16 + brow) * NN + kc + bcol);
    // A prefetch for the whole chunk (nontemporal: streamed once)
    f32x4 areg[8];
#pragma unroll
    for (int s = 0; s < 4; ++s) {
      areg[2 * s]     = __builtin_nontemporal_load((const f32x4*)(ap + c * KCHUNK + s * 32));
      areg[2 * s + 1] = __builtin_nontemporal_load((const f32x4*)(ap + c * KCHUNK + s * 32 + 4));
    }
#pragma unroll
    for (int rr = 0; rr < 9; ++rr)
      *(u32x4*)(bt + (rr * 16 + brow) * BSTRIDE + bcol) = breg[rr];
    __syncthreads();
#pragma unroll
    for (int s = 0; s < 4; ++s) {
      bf16x8 af = cvt2(areg[2 * s], areg[2 * s + 1]);
      const unsigned short* bp = bt + s * 32 + quad * 8;
#pragma unroll
      for (int nt = 0; nt < 9; ++nt) {
        bf16x8 bf = *(const bf16x8*)(bp + (nt * 16 + nlo) * BSTRIDE);
        acc[nt] = __builtin_amdgcn_mfma_f32_16x16x32_bf16(af, bf, acc[nt], 0, 0, 0);
      }
    }
    __syncthreads();
  }

  float* pbase = part + ((size_t)blockIdx.y * NN + rowW) * NB;
#pragma unroll
  for (int nt = 0; nt < 9; ++nt)
#pragma unroll
    for (int rg = 0; rg < 4; ++rg)
      pbase[(size_t)(quad * 4 + rg) * NB + nt * 16 + nlo] = acc[nt][rg];
}

// K3b: out[row][col] = relu( sum_s part[s][row][col] / sum_s part[s][row][128] )
__global__ __launch_bounds__(256) void k3_reduce(const float* __restrict__ part,
                                                 float* __restrict__ out) {
  const int col = threadIdx.x & 127;
  const int row = blockIdx.x * 2 + (threadIdx.x >> 7);
  float num = 0.f, den = 0.f;
#pragma unroll
  for (int s = 0; s < KSPLIT; ++s) {
    const size_t base = ((size_t)s * NN + row) * NB;
    num += part[base + col];
    den += part[base + 128];
  }
  out[(size_t)row * OUTD + col] = fmaxf(num / den, 0.f);
}

extern "C" void kernel_launch(void* const* d_in, const int* in_sizes, int n_in,
                              void* d_out, int out_size, void* d_ws, size_t ws_size,
                              hipStream_t stream) {
  const float* X  = (const float*)d_in[0];
  const float* A  = (const float*)d_in[1];
  const float* W  = (const float*)d_in[2];
  const float* aw = (const float*)d_in[3];
  float* out = (float*)d_out;

  char* ws = (char*)d_ws;
  float*  Wh   = (float*)ws;                    // 8192*128*4   = 4 MiB
  float*  ev   = (float*)(ws + 4194304);        // 8192*4       = 32 KiB
  __bf16* Bt   = (__bf16*)(ws + 4227072);       // 144*8192*2   = 2.25 MiB
  float*  part = (float*)(ws + 8388608);        // 8*8192*144*4 = 37.75 MiB

  k1_wh_e<<<256, 128, 0, stream>>>(X, W, aw, Wh, ev);
  k2_bt<<<dim3(32, 8), 256, 0, stream>>>(Wh, ev, Bt);
  k3_partial<<<dim3(128, KSPLIT), 256, 0, stream>>>(A, Bt, part);
  k3_reduce<<<4096, 256, 0, stream>>>(part, out);
}